// Round 9
// baseline (471.079 us; speedup 1.0000x reference)
//
#include <hip/hip_runtime.h>
#include <math.h>

#define S_LEN 512
#define D_DIM 256
#define SLICE (S_LEN * D_DIM)   // 131072

// exp2-domain constants: acc2 = L*log2e everywhere downstream of the MFMA.
#define LOG2E  1.44269504088896f
#define LN2    0.69314718055995f
#define C2     (8.0f * LOG2E)    // fixed shift (8.0 in e-domain); |L| <~ 12
                                 // so e^(L-8) in [e^-20, e^4] — safe in fp32.

// bare hardware v_exp_f32 (2^x). NOTE: __exp2f does NOT exist in HIP device
// code (glibc macro clash, R5 compile failure) — use the amdgcn builtin.
#define EXP2F(x) __builtin_amdgcn_exp2f(x)

typedef _Float16 half8  __attribute__((ext_vector_type(8)));
typedef _Float16 half4v __attribute__((ext_vector_type(4)));
typedef float   floatx4 __attribute__((ext_vector_type(4)));

// ---------------------------------------------------------------------------
// linres3 + prep_wl fused (blockIdx.y==3 does WlhT prep — saves a launch).
// y = x + x@W + b  for [512,256]@[256,256]; 4 rows/block (baseline shape).
// k,q cast to fp16 at the store (identical rounding to fp32-store + cvt).
// ---------------------------------------------------------------------------
__global__ __launch_bounds__(256) void linres3(
    const float* __restrict__ xk, const float* __restrict__ Wk,
    const float* __restrict__ bk, _Float16* __restrict__ yk16,
    const float* __restrict__ xq, const float* __restrict__ Wq,
    const float* __restrict__ bq, _Float16* __restrict__ yq16,
    const float* __restrict__ xv, const float* __restrict__ Wv,
    const float* __restrict__ bv, float* __restrict__ yv,
    const float* __restrict__ Wl, _Float16* __restrict__ WlhT)
{
    const int tid = threadIdx.x;
    const int sel = blockIdx.y;

    if (sel == 3) {
        // WlhT[d][e] = fp16((Wl[e][d] + (e==d)) * log2e); 2 d-rows per block
        #pragma unroll
        for (int t = 0; t < 2; ++t) {
            const int d = blockIdx.x * 2 + t;
            float v = (Wl[tid * D_DIM + d] + (tid == d ? 1.0f : 0.0f)) * LOG2E;
            WlhT[d * D_DIM + tid] = (_Float16)v;
        }
        return;
    }

    __shared__ float xs[4][D_DIM];
    const int r0 = blockIdx.x * 4;
    const float* x = sel == 0 ? xk : (sel == 1 ? xq : xv);
    const float* W = sel == 0 ? Wk : (sel == 1 ? Wq : Wv);
    const float* b = sel == 0 ? bk : (sel == 1 ? bq : bv);

    #pragma unroll
    for (int t = 0; t < 4; ++t) xs[t][tid] = x[(r0 + t) * D_DIM + tid];
    __syncthreads();
    const float bv_ = b[tid];
    float acc[4];
    #pragma unroll
    for (int i = 0; i < 4; ++i) acc[i] = xs[i][tid] + bv_;
    #pragma unroll 8
    for (int e = 0; e < D_DIM; ++e) {
        const float w = W[e * D_DIM + tid];
        #pragma unroll
        for (int i = 0; i < 4; ++i) acc[i] += xs[i][e] * w;
    }
    if (sel == 2) {
        #pragma unroll
        for (int i = 0; i < 4; ++i) yv[(r0 + i) * D_DIM + tid] = acc[i];
    } else {
        _Float16* y16 = sel == 0 ? yk16 : yq16;
        #pragma unroll
        for (int i = 0; i < 4; ++i) y16[(r0 + i) * D_DIM + tid] = (_Float16)acc[i];
    }
}

// ---------------------------------------------------------------------------
// Final linear with partial-sum fusion: x = sum_c po[c] (c<32 now);
// out = x + x@W + b.  2 rows/block -> 256 blocks; unroll 8.
// ---------------------------------------------------------------------------
__global__ __launch_bounds__(256) void linres_sum(
    const float* __restrict__ po, const float* __restrict__ W,
    const float* __restrict__ b, float* __restrict__ y)
{
    __shared__ float xs[2][D_DIM];
    const int tid = threadIdx.x;
    const int r0  = blockIdx.x * 2;
    #pragma unroll
    for (int t = 0; t < 2; ++t) {
        float s = 0.f;
        #pragma unroll
        for (int c = 0; c < 32; ++c)
            s += po[(size_t)c * SLICE + (r0 + t) * D_DIM + tid];
        xs[t][tid] = s;
    }
    __syncthreads();
    const float bv_ = b[tid];
    float acc[2];
    #pragma unroll
    for (int i = 0; i < 2; ++i) acc[i] = xs[i][tid] + bv_;
    #pragma unroll 8
    for (int e = 0; e < D_DIM; ++e) {
        const float w = W[e * D_DIM + tid];
        #pragma unroll
        for (int i = 0; i < 2; ++i) acc[i] += xs[i][e] * w;
    }
    #pragma unroll
    for (int i = 0; i < 2; ++i) y[(r0 + i) * D_DIM + tid] = acc[i];
}

// ---------------------------------------------------------------------------
// Stage 32x256 fp16 q tile into fragment-major LDS (mt in {0,1}), 4 half8
// per thread (R8-session-proven layout, shared by stats and accum now).
// ---------------------------------------------------------------------------
__device__ __forceinline__ void stage_q32(const _Float16* __restrict__ qh,
                                          _Float16* __restrict__ Afrag,
                                          int sq0, int tid)
{
    const int i   = tid & 31;   // row within tile
    const int oct = tid >> 5;   // e-eighth (32 halfs)
    const int mt = i >> 4, l16 = i & 15;
    const half8* src = (const half8*)(qh + (size_t)(sq0 + i) * D_DIM);
    #pragma unroll
    for (int u = 0; u < 4; ++u) {
        const int eb   = oct * 4 + u;           // e-block (8 halfs) 0..31
        const int kk   = eb >> 2, quad = eb & 3;
        const int addr16 = (mt * 8 + kk) * 64 + quad * 16 + l16;
        *(half8*)(Afrag + addr16 * 8) = src[eb];
    }
}

// ---------------------------------------------------------------------------
// Stats: per-(sk,d) tile-partial (max M2, S2 = sum |L2| 2^(L2-C2)) over a
// 32-sq tile, exp2 domain.
// R9 theory (from R8's falsification): occupancy was stuck at 2 waves/SIMD
// because TOTAL regs (128 VGPR + 32 AGPR acc[4][2] = 160) cross the 128
// bucket boundary (m69: waves/SIMD halves at 64/128/256 TOTAL, unified
// file). Fix: mt 4->2 -> acc 16 AGPR, live set ~120 total;
// launch_bounds(256, 4) forces the allocator into the 4-waves/EU budget.
// Grid (16,2,32) = 1024 blocks = 4 blocks/CU co-resident. LDS-read:MFMA
// ratio unchanged (1:2) — only one-time staging duplicates (unlike R3's
// y-split, which doubled per-s LDS traffic).
// kk loop FULLY unrolled (wl must stay static-indexed — the R7-R9 bug).
// ---------------------------------------------------------------------------
__global__ __launch_bounds__(256, 4) void stats_mfma(
    const _Float16* __restrict__ qh, const _Float16* __restrict__ kh,
    const _Float16* __restrict__ WlhT, const float* __restrict__ bl,
    float* __restrict__ pm, float* __restrict__ ps)
{
    __shared__ _Float16 Afrag[16 * 64 * 8];   // 16 KB

    const int tid  = threadIdx.x;
    const int lane = tid & 63, wave = tid >> 6;
    const int quad = lane >> 4, l16 = lane & 15;
    const int sqt  = blockIdx.x, sq0 = sqt * 32;
    const int dw   = blockIdx.y * 128 + wave * 32;
    const int sk0  = blockIdx.z * 16;

    stage_q32(qh, Afrag, sq0, tid);

    half8 wl[2][8];
    #pragma unroll
    for (int nt = 0; nt < 2; ++nt) {
        const int d = dw + nt * 16 + l16;
        #pragma unroll
        for (int kk = 0; kk < 8; ++kk)
            wl[nt][kk] = *(const half8*)(WlhT + (size_t)d * D_DIM + kk * 32 + quad * 8);
    }
    float bl_r[2];
    #pragma unroll
    for (int nt = 0; nt < 2; ++nt)
        bl_r[nt] = bl[dw + nt * 16 + l16] * LOG2E;

    __syncthreads();

    #pragma unroll 1
    for (int s = 0; s < 16; ++s) {
        const int sk = sk0 + s;
        floatx4 acc[2][2];
        #pragma unroll
        for (int mt = 0; mt < 2; ++mt)
            #pragma unroll
            for (int nt = 0; nt < 2; ++nt)
                acc[mt][nt] = (floatx4){0.f, 0.f, 0.f, 0.f};

        #pragma unroll
        for (int kk = 0; kk < 8; ++kk) {
            const half8 k8 = *(const half8*)(kh + (size_t)sk * D_DIM + kk * 32 + quad * 8);
            half8 af[2], bf[2];
            #pragma unroll
            for (int mt = 0; mt < 2; ++mt)
                af[mt] = *(const half8*)(Afrag + ((mt * 8 + kk) * 64 + lane) * 8);
            #pragma unroll
            for (int nt = 0; nt < 2; ++nt)
                bf[nt] = wl[nt][kk] * k8;
            #pragma unroll
            for (int mt = 0; mt < 2; ++mt)
                #pragma unroll
                for (int nt = 0; nt < 2; ++nt)
                    acc[mt][nt] = __builtin_amdgcn_mfma_f32_16x16x32_f16(
                        af[mt], bf[nt], acc[mt][nt], 0, 0, 0);
        }

        #pragma unroll
        for (int nt = 0; nt < 2; ++nt) {
            // per-mt depth-2 trees, then cross-mt combine (ILP-friendly)
            float mmx[2], tss[2];
            #pragma unroll
            for (int mt = 0; mt < 2; ++mt) {
                float L0 = acc[mt][nt][0] + bl_r[nt];
                float L1 = acc[mt][nt][1] + bl_r[nt];
                float L2 = acc[mt][nt][2] + bl_r[nt];
                float L3 = acc[mt][nt][3] + bl_r[nt];
                float t0 = fabsf(L0) * EXP2F(L0 - C2);
                float t1 = fabsf(L1) * EXP2F(L1 - C2);
                float t2 = fabsf(L2) * EXP2F(L2 - C2);
                float t3 = fabsf(L3) * EXP2F(L3 - C2);
                mmx[mt] = fmaxf(fmaxf(L0, L1), fmaxf(L2, L3));
                tss[mt] = (t0 + t1) + (t2 + t3);
            }
            float m  = fmaxf(mmx[0], mmx[1]);
            float ss = tss[0] + tss[1];

            // fixed-C: plain butterfly (no rescale exps)
            #pragma unroll
            for (int mask = 16; mask <= 32; mask <<= 1) {
                m  = fmaxf(m, __shfl_xor(m, mask, 64));
                ss += __shfl_xor(ss, mask, 64);
            }
            if (quad == 0) {
                const int d = dw + nt * 16 + l16;
                pm[((size_t)sqt * S_LEN + sk) * D_DIM + d] = m;
                ps[((size_t)sqt * S_LEN + sk) * D_DIM + d] = ss;
            }
        }
    }
}

// ---------------------------------------------------------------------------
// Merge 16 sq-tile partials and pre-fold EVERYTHING accum needs into one
// stream. exp2 domain: denom_true = LN2*S2_total + 2^(M2-C2);
// wbuf = v * LN2 / denom_true   (the LN2 converts accum's acc2 back to L).
// ---------------------------------------------------------------------------
__global__ __launch_bounds__(256) void reduce_ms(
    const float* __restrict__ pm, const float* __restrict__ ps,
    const float* __restrict__ vbuf, float* __restrict__ wbuf)
{
    const int idx = blockIdx.x * 256 + threadIdx.x;   // (sk,d), 131072 total
    float M = -1e30f, S = 0.f;
    #pragma unroll
    for (int t = 0; t < 16; ++t) {
        M = fmaxf(M, pm[(size_t)t * SLICE + idx]);
        S += ps[(size_t)t * SLICE + idx];
    }
    const float denom = S * LN2 + EXP2F(M - C2);
    wbuf[idx] = vbuf[idx] * (LN2 / denom);
}

// ---------------------------------------------------------------------------
// Accum: recompute L2; o += wbuf[sk,d] * acc2 * 2^(acc2-C2) over 16 sk.
// R9: the R7 amdgpu_waves_per_eu(2,2) PINNED max occupancy at 2 waves/EU —
// removed. launch_bounds(256,4) + z 16->32 (1024 blocks, s-loop 16) lets
// 4 blocks/CU co-reside (96 VGPR + 32 AGPR = 128 total = 4-wave bucket).
// Software pipelining of k8/wbuf (R7) kept. po now 32 chunks.
// ---------------------------------------------------------------------------
__global__ __launch_bounds__(256, 4) void accum_mfma(
    const _Float16* __restrict__ qh, const _Float16* __restrict__ kh,
    const _Float16* __restrict__ WlhT, const float* __restrict__ bl,
    const float* __restrict__ wbuf, float* __restrict__ po)
{
    __shared__ _Float16 Afrag[16 * 64 * 8];   // 16 KB

    const int tid  = threadIdx.x;
    const int lane = tid & 63, wave = tid >> 6;
    const int quad = lane >> 4, l16 = lane & 15;
    const int sq0  = blockIdx.x * 32;
    const int dw   = blockIdx.y * 128 + wave * 32;
    const int chunk = blockIdx.z;
    const int sk0  = chunk * 16;

    stage_q32(qh, Afrag, sq0, tid);

    half8 wl[2][8];
    #pragma unroll
    for (int nt = 0; nt < 2; ++nt) {
        const int d = dw + nt * 16 + l16;
        #pragma unroll
        for (int kk = 0; kk < 8; ++kk)
            wl[nt][kk] = *(const half8*)(WlhT + (size_t)d * D_DIM + kk * 32 + quad * 8);
    }
    float bl_r[2];
    #pragma unroll
    for (int nt = 0; nt < 2; ++nt)
        bl_r[nt] = bl[dw + nt * 16 + l16] * LOG2E;

    __syncthreads();

    // One-time reg-fill of A fragments.
    half8 afr[2][8];
    #pragma unroll
    for (int mt = 0; mt < 2; ++mt)
        #pragma unroll
        for (int kk = 0; kk < 8; ++kk)
            afr[mt][kk] = *(const half8*)(Afrag + ((mt * 8 + kk) * 64 + lane) * 8);

    floatx4 o[2][2];
    #pragma unroll
    for (int mt = 0; mt < 2; ++mt)
        #pragma unroll
        for (int nt = 0; nt < 2; ++nt)
            o[mt][nt] = (floatx4){0.f, 0.f, 0.f, 0.f};

    // prologue: prefetch k8 + wbuf for s=0
    half8 k8c[8];
    #pragma unroll
    for (int kk = 0; kk < 8; ++kk)
        k8c[kk] = *(const half8*)(kh + (size_t)sk0 * D_DIM + kk * 32 + quad * 8);
    float w_c0 = wbuf[(size_t)sk0 * D_DIM + dw + l16];
    float w_c1 = wbuf[(size_t)sk0 * D_DIM + dw + 16 + l16];

    #pragma unroll 1
    for (int s = 0; s < 16; ++s) {
        const int sk = sk0 + s;

        floatx4 acc[2][2];
        #pragma unroll
        for (int mt = 0; mt < 2; ++mt)
            #pragma unroll
            for (int nt = 0; nt < 2; ++nt)
                acc[mt][nt] = (floatx4){0.f, 0.f, 0.f, 0.f};

        #pragma unroll
        for (int kk = 0; kk < 8; ++kk) {
            const half8 bf0 = wl[0][kk] * k8c[kk];
            const half8 bf1 = wl[1][kk] * k8c[kk];
            acc[0][0] = __builtin_amdgcn_mfma_f32_16x16x32_f16(afr[0][kk], bf0, acc[0][0], 0, 0, 0);
            acc[0][1] = __builtin_amdgcn_mfma_f32_16x16x32_f16(afr[0][kk], bf1, acc[0][1], 0, 0, 0);
            acc[1][0] = __builtin_amdgcn_mfma_f32_16x16x32_f16(afr[1][kk], bf0, acc[1][0], 0, 0, 0);
            acc[1][1] = __builtin_amdgcn_mfma_f32_16x16x32_f16(afr[1][kk], bf1, acc[1][1], 0, 0, 0);
        }

        // snapshot current scalars, then issue NEXT iteration's loads so
        // their latency hides under the exp epilogue below.
        const float w_use0 = w_c0, w_use1 = w_c1;
        if (s < 15) {
            #pragma unroll
            for (int kk = 0; kk < 8; ++kk)
                k8c[kk] = *(const half8*)(kh + (size_t)(sk + 1) * D_DIM + kk * 32 + quad * 8);
            w_c0 = wbuf[(size_t)(sk + 1) * D_DIM + dw + l16];
            w_c1 = wbuf[(size_t)(sk + 1) * D_DIM + dw + 16 + l16];
        }

        #pragma unroll
        for (int mt = 0; mt < 2; ++mt)
            #pragma unroll
            for (int r = 0; r < 4; ++r) {
                const float La = acc[mt][0][r] + bl_r[0];
                const float Lb = acc[mt][1][r] + bl_r[1];
                o[mt][0][r] += w_use0 * (La * EXP2F(La - C2));
                o[mt][1][r] += w_use1 * (Lb * EXP2F(Lb - C2));
            }
    }

    float* dst = po + (size_t)chunk * SLICE;
    #pragma unroll
    for (int mt = 0; mt < 2; ++mt)
        #pragma unroll
        for (int nt = 0; nt < 2; ++nt)
            #pragma unroll
            for (int r = 0; r < 4; ++r) {
                const int row = sq0 + mt * 16 + quad * 4 + r;
                const int col = dw + nt * 16 + l16;
                dst[(size_t)row * D_DIM + col] = o[mt][nt][r];
            }
}

// ---------------------------------------------------------------------------
extern "C" void kernel_launch(void* const* d_in, const int* in_sizes, int n_in,
                              void* d_out, int out_size, void* d_ws, size_t ws_size,
                              hipStream_t stream)
{
    const float* query = (const float*)d_in[0];
    const float* key   = (const float*)d_in[1];
    const float* value = (const float*)d_in[2];
    const float* Wk  = (const float*)d_in[3];
    const float* bk  = (const float*)d_in[4];
    const float* Wq  = (const float*)d_in[5];
    const float* bq  = (const float*)d_in[6];
    const float* Wva = (const float*)d_in[7];
    const float* bva = (const float*)d_in[8];
    const float* Wl  = (const float*)d_in[9];
    const float* bl  = (const float*)d_in[10];
    const float* Wvo = (const float*)d_in[11];
    const float* bvo = (const float*)d_in[12];

    const int MAT = SLICE;                    // 131072
    float* ws   = (float*)d_ws;
    // R9 compacted layout. Extent = 425984 + 32*SLICE floats ~= 18.5 MB
    // (was ~11.6 MB): pm/ps now 16 sq-tile slices each; po (32 chunks,
    // 16 MB) overlays pm+ps which are dead after reduce_ms.
    float* vbuf = ws;                                      // 0.5 MB
    float* wbuf = ws + MAT;                                // 0.5 MB
    _Float16* WlhT = (_Float16*)(ws + 2 * MAT);            // 128 KB
    _Float16* kh   = (_Float16*)(ws + 2 * MAT + 32768);    // 256 KB
    _Float16* qh   = kh + MAT;                             // 256 KB
    float* pm  = ws + 2 * MAT + 32768 + 2 * 65536;         // 8 MB (16 slices)
    float* ps  = pm + 16 * MAT;                            // 8 MB (16 slices)
    float* po  = pm;   // 32*MAT floats (16 MB) spans pm+ps
    float* out = (float*)d_out;

    linres3<<<dim3(128, 4), 256, 0, stream>>>(key, Wk, bk, kh,
                                              query, Wq, bq, qh,
                                              value, Wva, bva, vbuf,
                                              Wl, WlhT);

    stats_mfma<<<dim3(16, 2, 32), 256, 0, stream>>>(qh, kh, WlhT, bl, pm, ps);
    reduce_ms<<<512, 256, 0, stream>>>(pm, ps, vbuf, wbuf);
    accum_mfma<<<dim3(16, 2, 32), 256, 0, stream>>>(qh, kh, WlhT, bl,
                                                    wbuf, po);

    linres_sum<<<256, 256, 0, stream>>>(po, Wvo, bvo, out);
}

// Round 10
// 194.184 us; speedup vs baseline: 2.4259x; 2.4259x over previous
//
#include <hip/hip_runtime.h>
#include <math.h>

#define S_LEN 512
#define D_DIM 256
#define SLICE (S_LEN * D_DIM)   // 131072

// exp2-domain constants: acc2 = L*log2e everywhere downstream of the MFMA.
#define LOG2E  1.44269504088896f
#define LN2    0.69314718055995f
#define C2     (8.0f * LOG2E)    // fixed shift (8.0 in e-domain); |L| <~ 12
                                 // so e^(L-8) in [e^-20, e^4] — safe in fp32.

// bare hardware v_exp_f32 (2^x). NOTE: __exp2f does NOT exist in HIP device
// code (glibc macro clash, R5 compile failure) — use the amdgcn builtin.
#define EXP2F(x) __builtin_amdgcn_exp2f(x)

// OCCUPANCY LADDER (measured, rounds 0-9):
//  - live set > 128 total regs (VGPR+AGPR unified) + launch_bounds/waves_per_eu
//    requesting 4 waves/EU  => catastrophic scratch spill (R4: 41MB, R7: 43MB,
//    R9: 870MB of FETCH+WRITE round-trip).
//  - honest ~160-190-reg live set => clean 2 waves/SIMD (R2/R6/R7/R8).
//  - more blocks at 2 waves/SIMD => no added co-residency, only duplicated
//    staging (R8 stats z=64: 56->62us; R0 accum sq-split: 2.3x worse).
//  2 waves/SIMD is structural for these MFMA kernels. Do not fight it.

typedef _Float16 half8  __attribute__((ext_vector_type(8)));
typedef _Float16 half4v __attribute__((ext_vector_type(4)));
typedef float   floatx4 __attribute__((ext_vector_type(4)));

// ---------------------------------------------------------------------------
// linres3 + prep_wl fused (blockIdx.y==3 does WlhT prep — saves a launch).
// y = x + x@W + b  for [512,256]@[256,256]; 4 rows/block (baseline shape).
// k,q cast to fp16 at the store (identical rounding to fp32-store + cvt).
// ---------------------------------------------------------------------------
__global__ __launch_bounds__(256) void linres3(
    const float* __restrict__ xk, const float* __restrict__ Wk,
    const float* __restrict__ bk, _Float16* __restrict__ yk16,
    const float* __restrict__ xq, const float* __restrict__ Wq,
    const float* __restrict__ bq, _Float16* __restrict__ yq16,
    const float* __restrict__ xv, const float* __restrict__ Wv,
    const float* __restrict__ bv, float* __restrict__ yv,
    const float* __restrict__ Wl, _Float16* __restrict__ WlhT)
{
    const int tid = threadIdx.x;
    const int sel = blockIdx.y;

    if (sel == 3) {
        // WlhT[d][e] = fp16((Wl[e][d] + (e==d)) * log2e); 2 d-rows per block
        #pragma unroll
        for (int t = 0; t < 2; ++t) {
            const int d = blockIdx.x * 2 + t;
            float v = (Wl[tid * D_DIM + d] + (tid == d ? 1.0f : 0.0f)) * LOG2E;
            WlhT[d * D_DIM + tid] = (_Float16)v;
        }
        return;
    }

    __shared__ float xs[4][D_DIM];
    const int r0 = blockIdx.x * 4;
    const float* x = sel == 0 ? xk : (sel == 1 ? xq : xv);
    const float* W = sel == 0 ? Wk : (sel == 1 ? Wq : Wv);
    const float* b = sel == 0 ? bk : (sel == 1 ? bq : bv);

    #pragma unroll
    for (int t = 0; t < 4; ++t) xs[t][tid] = x[(r0 + t) * D_DIM + tid];
    __syncthreads();
    const float bv_ = b[tid];
    float acc[4];
    #pragma unroll
    for (int i = 0; i < 4; ++i) acc[i] = xs[i][tid] + bv_;
    #pragma unroll 8
    for (int e = 0; e < D_DIM; ++e) {
        const float w = W[e * D_DIM + tid];
        #pragma unroll
        for (int i = 0; i < 4; ++i) acc[i] += xs[i][e] * w;
    }
    if (sel == 2) {
        #pragma unroll
        for (int i = 0; i < 4; ++i) yv[(r0 + i) * D_DIM + tid] = acc[i];
    } else {
        _Float16* y16 = sel == 0 ? yk16 : yq16;
        #pragma unroll
        for (int i = 0; i < 4; ++i) y16[(r0 + i) * D_DIM + tid] = (_Float16)acc[i];
    }
}

// ---------------------------------------------------------------------------
// Final linear with partial-sum fusion: x = sum_c po[c]; out = x + x@W + b
// 2 rows/block -> 256 blocks; unroll 8.  (R8-proven)
// ---------------------------------------------------------------------------
__global__ __launch_bounds__(256) void linres_sum(
    const float* __restrict__ po, const float* __restrict__ W,
    const float* __restrict__ b, float* __restrict__ y)
{
    __shared__ float xs[2][D_DIM];
    const int tid = threadIdx.x;
    const int r0  = blockIdx.x * 2;
    #pragma unroll
    for (int t = 0; t < 2; ++t) {
        float s = 0.f;
        #pragma unroll
        for (int c = 0; c < 16; ++c)
            s += po[(size_t)c * SLICE + (r0 + t) * D_DIM + tid];
        xs[t][tid] = s;
    }
    __syncthreads();
    const float bv_ = b[tid];
    float acc[2];
    #pragma unroll
    for (int i = 0; i < 2; ++i) acc[i] = xs[i][tid] + bv_;
    #pragma unroll 8
    for (int e = 0; e < D_DIM; ++e) {
        const float w = W[e * D_DIM + tid];
        #pragma unroll
        for (int i = 0; i < 2; ++i) acc[i] += xs[i][e] * w;
    }
    #pragma unroll
    for (int i = 0; i < 2; ++i) y[(r0 + i) * D_DIM + tid] = acc[i];
}

// ---------------------------------------------------------------------------
// Stage 64x256 fp16 q tile into fragment-major LDS (session-proven):
// fb = mt*8+kk; slot = quad*16+l16; addr16 = fb*64 + slot. Conflict-free.
// ---------------------------------------------------------------------------
__device__ __forceinline__ void stage_q(const _Float16* __restrict__ qh,
                                        _Float16* __restrict__ Afrag,
                                        int sq0, int tid)
{
    const int i   = tid & 63;   // row within tile
    const int qtr = tid >> 6;   // e-quarter (64 elems)
    const int mt = i >> 4, l16 = i & 15;
    const half8* src = (const half8*)(qh + (size_t)(sq0 + i) * D_DIM + qtr * 64);
    #pragma unroll
    for (int u = 0; u < 8; ++u) {
        const int eb   = qtr * 8 + u;           // e-block (8 halfs) 0..31
        const int kk   = eb >> 2, quad = eb & 3;
        const int addr16 = (mt * 8 + kk) * 64 + quad * 16 + l16;
        *(half8*)(Afrag + addr16 * 8) = src[u];
    }
}

// Same layout for a 32-row tile (mt in {0,1}), 4 half8 per thread.
__device__ __forceinline__ void stage_q32(const _Float16* __restrict__ qh,
                                          _Float16* __restrict__ Afrag,
                                          int sq0, int tid)
{
    const int i   = tid & 31;   // row within tile
    const int oct = tid >> 5;   // e-eighth (32 halfs)
    const int mt = i >> 4, l16 = i & 15;
    const half8* src = (const half8*)(qh + (size_t)(sq0 + i) * D_DIM);
    #pragma unroll
    for (int u = 0; u < 4; ++u) {
        const int eb   = oct * 4 + u;           // e-block (8 halfs) 0..31
        const int kk   = eb >> 2, quad = eb & 3;
        const int addr16 = (mt * 8 + kk) * 64 + quad * 16 + l16;
        *(half8*)(Afrag + addr16 * 8) = src[eb];
    }
}

// ---------------------------------------------------------------------------
// Stats: per-(sk,d) tile-partial (max M2, S2 = sum |L2| 2^(L2-C2)) over 64
// sq rows, exp2 domain. EXACT R6 config — grid (8,2,32), s-loop 16 — the
// fastest measured variant (56.3us). R8's z=64 split regressed to 62us
// (no co-residency gain at 2 waves/SIMD, extra staging). 128 VGPR + 32
// AGPR = 160 total => 2 waves/SIMD, clean (no spill).
// kk loop FULLY unrolled (wl must stay static-indexed).
// ---------------------------------------------------------------------------
__global__ __launch_bounds__(256, 2) void stats_mfma(
    const _Float16* __restrict__ qh, const _Float16* __restrict__ kh,
    const _Float16* __restrict__ WlhT, const float* __restrict__ bl,
    float* __restrict__ pm, float* __restrict__ ps)
{
    __shared__ _Float16 Afrag[32 * 64 * 8];   // 32 KB

    const int tid  = threadIdx.x;
    const int lane = tid & 63, wave = tid >> 6;
    const int quad = lane >> 4, l16 = lane & 15;
    const int sqt  = blockIdx.x, sq0 = sqt * 64;
    const int dw   = blockIdx.y * 128 + wave * 32;
    const int sk0  = blockIdx.z * 16;

    stage_q(qh, Afrag, sq0, tid);

    half8 wl[2][8];
    #pragma unroll
    for (int nt = 0; nt < 2; ++nt) {
        const int d = dw + nt * 16 + l16;
        #pragma unroll
        for (int kk = 0; kk < 8; ++kk)
            wl[nt][kk] = *(const half8*)(WlhT + (size_t)d * D_DIM + kk * 32 + quad * 8);
    }
    float bl_r[2];
    #pragma unroll
    for (int nt = 0; nt < 2; ++nt)
        bl_r[nt] = bl[dw + nt * 16 + l16] * LOG2E;

    __syncthreads();

    #pragma unroll 1
    for (int s = 0; s < 16; ++s) {
        const int sk = sk0 + s;
        floatx4 acc[4][2];
        #pragma unroll
        for (int mt = 0; mt < 4; ++mt)
            #pragma unroll
            for (int nt = 0; nt < 2; ++nt)
                acc[mt][nt] = (floatx4){0.f, 0.f, 0.f, 0.f};

        #pragma unroll
        for (int kk = 0; kk < 8; ++kk) {
            const half8 k8 = *(const half8*)(kh + (size_t)sk * D_DIM + kk * 32 + quad * 8);
            half8 af[4], bf[2];
            #pragma unroll
            for (int mt = 0; mt < 4; ++mt)
                af[mt] = *(const half8*)(Afrag + ((mt * 8 + kk) * 64 + lane) * 8);
            #pragma unroll
            for (int nt = 0; nt < 2; ++nt)
                bf[nt] = wl[nt][kk] * k8;
            #pragma unroll
            for (int mt = 0; mt < 4; ++mt)
                #pragma unroll
                for (int nt = 0; nt < 2; ++nt)
                    acc[mt][nt] = __builtin_amdgcn_mfma_f32_16x16x32_f16(
                        af[mt], bf[nt], acc[mt][nt], 0, 0, 0);
        }

        #pragma unroll
        for (int nt = 0; nt < 2; ++nt) {
            // per-mt depth-2 trees, then cross-mt tree (ILP-friendly)
            float mmx[4], tss[4];
            #pragma unroll
            for (int mt = 0; mt < 4; ++mt) {
                float L0 = acc[mt][nt][0] + bl_r[nt];
                float L1 = acc[mt][nt][1] + bl_r[nt];
                float L2 = acc[mt][nt][2] + bl_r[nt];
                float L3 = acc[mt][nt][3] + bl_r[nt];
                float t0 = fabsf(L0) * EXP2F(L0 - C2);
                float t1 = fabsf(L1) * EXP2F(L1 - C2);
                float t2 = fabsf(L2) * EXP2F(L2 - C2);
                float t3 = fabsf(L3) * EXP2F(L3 - C2);
                mmx[mt] = fmaxf(fmaxf(L0, L1), fmaxf(L2, L3));
                tss[mt] = (t0 + t1) + (t2 + t3);
            }
            float m  = fmaxf(fmaxf(mmx[0], mmx[1]), fmaxf(mmx[2], mmx[3]));
            float ss = (tss[0] + tss[1]) + (tss[2] + tss[3]);

            // fixed-C: plain butterfly (no rescale exps)
            #pragma unroll
            for (int mask = 16; mask <= 32; mask <<= 1) {
                m  = fmaxf(m, __shfl_xor(m, mask, 64));
                ss += __shfl_xor(ss, mask, 64);
            }
            if (quad == 0) {
                const int d = dw + nt * 16 + l16;
                pm[((size_t)sqt * S_LEN + sk) * D_DIM + d] = m;
                ps[((size_t)sqt * S_LEN + sk) * D_DIM + d] = ss;
            }
        }
    }
}

// ---------------------------------------------------------------------------
// Merge 8 sq-tile partials and pre-fold EVERYTHING accum needs into one
// stream. exp2 domain: denom_true = LN2*S2_total + 2^(M2-C2);
// wbuf = v * LN2 / denom_true   (the LN2 converts accum's acc2 back to L).
// ---------------------------------------------------------------------------
__global__ __launch_bounds__(256) void reduce_ms(
    const float* __restrict__ pm, const float* __restrict__ ps,
    const float* __restrict__ vbuf, float* __restrict__ wbuf)
{
    const int idx = blockIdx.x * 256 + threadIdx.x;   // (sk,d), 131072 total
    float mv[8], sv[8];
    #pragma unroll
    for (int t = 0; t < 8; ++t) {
        mv[t] = pm[(size_t)t * SLICE + idx];
        sv[t] = ps[(size_t)t * SLICE + idx];
    }
    float M = fmaxf(fmaxf(fmaxf(mv[0], mv[1]), fmaxf(mv[2], mv[3])),
                    fmaxf(fmaxf(mv[4], mv[5]), fmaxf(mv[6], mv[7])));
    float S = ((sv[0] + sv[1]) + (sv[2] + sv[3]))
            + ((sv[4] + sv[5]) + (sv[6] + sv[7]));
    const float denom = S * LN2 + EXP2F(M - C2);
    wbuf[idx] = vbuf[idx] * (LN2 / denom);
}

// ---------------------------------------------------------------------------
// Accum: recompute L2; o += wbuf[sk,d] * acc2 * 2^(acc2-C2) over 32 sk.
// EXACT R7/R8 config (56.4us measured): software-pipelined k8/wbuf (loads
// for s+1 issued between MFMA burst and exp epilogue), grid (16,2,16),
// waves_per_eu(2,2) — the pin matches the structural 2-waves/SIMD regime;
// removing it + requesting 4 waves/EU spilled 870MB (R9).
// ---------------------------------------------------------------------------
__global__ __launch_bounds__(256)
__attribute__((amdgpu_waves_per_eu(2, 2)))
void accum_mfma(
    const _Float16* __restrict__ qh, const _Float16* __restrict__ kh,
    const _Float16* __restrict__ WlhT, const float* __restrict__ bl,
    const float* __restrict__ wbuf, float* __restrict__ po)
{
    __shared__ _Float16 Afrag[16 * 64 * 8];   // 16 KB

    const int tid  = threadIdx.x;
    const int lane = tid & 63, wave = tid >> 6;
    const int quad = lane >> 4, l16 = lane & 15;
    const int sq0  = blockIdx.x * 32;
    const int dw   = blockIdx.y * 128 + wave * 32;
    const int chunk = blockIdx.z;
    const int sk0  = chunk * 32;

    stage_q32(qh, Afrag, sq0, tid);

    half8 wl[2][8];
    #pragma unroll
    for (int nt = 0; nt < 2; ++nt) {
        const int d = dw + nt * 16 + l16;
        #pragma unroll
        for (int kk = 0; kk < 8; ++kk)
            wl[nt][kk] = *(const half8*)(WlhT + (size_t)d * D_DIM + kk * 32 + quad * 8);
    }
    float bl_r[2];
    #pragma unroll
    for (int nt = 0; nt < 2; ++nt)
        bl_r[nt] = bl[dw + nt * 16 + l16] * LOG2E;

    __syncthreads();

    // One-time reg-fill of A fragments.
    half8 afr[2][8];
    #pragma unroll
    for (int mt = 0; mt < 2; ++mt)
        #pragma unroll
        for (int kk = 0; kk < 8; ++kk)
            afr[mt][kk] = *(const half8*)(Afrag + ((mt * 8 + kk) * 64 + lane) * 8);

    floatx4 o[2][2];
    #pragma unroll
    for (int mt = 0; mt < 2; ++mt)
        #pragma unroll
        for (int nt = 0; nt < 2; ++nt)
            o[mt][nt] = (floatx4){0.f, 0.f, 0.f, 0.f};

    // prologue: prefetch k8 + wbuf for s=0
    half8 k8c[8];
    #pragma unroll
    for (int kk = 0; kk < 8; ++kk)
        k8c[kk] = *(const half8*)(kh + (size_t)sk0 * D_DIM + kk * 32 + quad * 8);
    float w_c0 = wbuf[(size_t)sk0 * D_DIM + dw + l16];
    float w_c1 = wbuf[(size_t)sk0 * D_DIM + dw + 16 + l16];

    #pragma unroll 1
    for (int s = 0; s < 32; ++s) {
        const int sk = sk0 + s;

        floatx4 acc[2][2];
        #pragma unroll
        for (int mt = 0; mt < 2; ++mt)
            #pragma unroll
            for (int nt = 0; nt < 2; ++nt)
                acc[mt][nt] = (floatx4){0.f, 0.f, 0.f, 0.f};

        #pragma unroll
        for (int kk = 0; kk < 8; ++kk) {
            const half8 bf0 = wl[0][kk] * k8c[kk];
            const half8 bf1 = wl[1][kk] * k8c[kk];
            acc[0][0] = __builtin_amdgcn_mfma_f32_16x16x32_f16(afr[0][kk], bf0, acc[0][0], 0, 0, 0);
            acc[0][1] = __builtin_amdgcn_mfma_f32_16x16x32_f16(afr[0][kk], bf1, acc[0][1], 0, 0, 0);
            acc[1][0] = __builtin_amdgcn_mfma_f32_16x16x32_f16(afr[1][kk], bf0, acc[1][0], 0, 0, 0);
            acc[1][1] = __builtin_amdgcn_mfma_f32_16x16x32_f16(afr[1][kk], bf1, acc[1][1], 0, 0, 0);
        }

        // snapshot current scalars, then issue NEXT iteration's loads so
        // their latency hides under the exp epilogue below.
        const float w_use0 = w_c0, w_use1 = w_c1;
        if (s < 31) {
            #pragma unroll
            for (int kk = 0; kk < 8; ++kk)
                k8c[kk] = *(const half8*)(kh + (size_t)(sk + 1) * D_DIM + kk * 32 + quad * 8);
            w_c0 = wbuf[(size_t)(sk + 1) * D_DIM + dw + l16];
            w_c1 = wbuf[(size_t)(sk + 1) * D_DIM + dw + 16 + l16];
        }

        #pragma unroll
        for (int mt = 0; mt < 2; ++mt)
            #pragma unroll
            for (int r = 0; r < 4; ++r) {
                const float La = acc[mt][0][r] + bl_r[0];
                const float Lb = acc[mt][1][r] + bl_r[1];
                o[mt][0][r] += w_use0 * (La * EXP2F(La - C2));
                o[mt][1][r] += w_use1 * (Lb * EXP2F(Lb - C2));
            }
    }

    float* dst = po + (size_t)chunk * SLICE;
    #pragma unroll
    for (int mt = 0; mt < 2; ++mt)
        #pragma unroll
        for (int nt = 0; nt < 2; ++nt)
            #pragma unroll
            for (int r = 0; r < 4; ++r) {
                const int row = sq0 + mt * 16 + quad * 4 + r;
                const int col = dw + nt * 16 + l16;
                dst[(size_t)row * D_DIM + col] = o[mt][nt][r];
            }
}

// ---------------------------------------------------------------------------
extern "C" void kernel_launch(void* const* d_in, const int* in_sizes, int n_in,
                              void* d_out, int out_size, void* d_ws, size_t ws_size,
                              hipStream_t stream)
{
    const float* query = (const float*)d_in[0];
    const float* key   = (const float*)d_in[1];
    const float* value = (const float*)d_in[2];
    const float* Wk  = (const float*)d_in[3];
    const float* bk  = (const float*)d_in[4];
    const float* Wq  = (const float*)d_in[5];
    const float* bq  = (const float*)d_in[6];
    const float* Wva = (const float*)d_in[7];
    const float* bva = (const float*)d_in[8];
    const float* Wl  = (const float*)d_in[9];
    const float* bl  = (const float*)d_in[10];
    const float* Wvo = (const float*)d_in[11];
    const float* bvo = (const float*)d_in[12];

    const int MAT = SLICE;                    // 131072
    float* ws   = (float*)d_ws;
    // R8-proven footprint (~12 MB): pm/ps 8 slices; po (16 chunks, 8 MB)
    // overlays pm+ps which are dead after reduce_ms.
    float* vbuf = ws + 2 * MAT;
    float* wbuf = ws + 3 * MAT;
    _Float16* WlhT = (_Float16*)(ws + 6 * MAT);            // 128 KB
    _Float16* kh   = (_Float16*)(ws + 6 * MAT + 32768);    // 256 KB
    _Float16* qh   = kh + MAT;                             // 256 KB
    float* pm  = ws + 6 * MAT + 32768 + 2 * 65536;         // 4 MB
    float* ps  = pm + 8 * MAT;                             // 4 MB
    float* po  = pm;   // 16*MAT floats (8 MB), pm/ps dead after reduce_ms
    float* out = (float*)d_out;

    linres3<<<dim3(128, 4), 256, 0, stream>>>(key, Wk, bk, kh,
                                              query, Wq, bq, qh,
                                              value, Wva, bva, vbuf,
                                              Wl, WlhT);

    stats_mfma<<<dim3(8, 2, 32), 256, 0, stream>>>(qh, kh, WlhT, bl, pm, ps);
    reduce_ms<<<512, 256, 0, stream>>>(pm, ps, vbuf, wbuf);
    accum_mfma<<<dim3(16, 2, 16), 256, 0, stream>>>(qh, kh, WlhT, bl,
                                                    wbuf, po);

    linres_sum<<<256, 256, 0, stream>>>(po, Wvo, bvo, out);
}